// Round 1
// baseline (721.474 us; speedup 1.0000x reference)
//
#include <hip/hip_runtime.h>
#include <stdint.h>
#include <string.h>

#define NLEV 16

// ---------------------------------------------------------------------------
// Shared helpers
// ---------------------------------------------------------------------------
__device__ __forceinline__ void norm_coords(const float* __restrict__ xyz, int p,
                                            float& nx, float& ny, float& nz) {
    const float x = __builtin_nontemporal_load(xyz + 3 * p + 0);
    const float y = __builtin_nontemporal_load(xyz + 3 * p + 1);
    const float z = __builtin_nontemporal_load(xyz + 3 * p + 2);
    const float inv = 1.0f / 1.5f;
    nx = (x + 0.75f) * inv;
    ny = (y + 0.75f) * inv;
    nz = (z + 0.75f) * inv;
}

template<int R>
__device__ __forceinline__ void big_prep(float nx, float ny, float nz,
                                         uint32_t h[8],
                                         float& fx, float& fy, float& fz) {
    const float rf = (float)R;
    const float px = nx * rf, py = ny * rf, pz = nz * rf;
    int bx = (int)floorf(px); bx = bx < 0 ? 0 : (bx > R - 1 ? R - 1 : bx);
    int by = (int)floorf(py); by = by < 0 ? 0 : (by > R - 1 ? R - 1 : by);
    int bz = (int)floorf(pz); bz = bz < 0 ? 0 : (bz > R - 1 ? R - 1 : bz);
    fx = px - (float)bx;
    fy = py - (float)by;
    fz = pz - (float)bz;

    // pow2 size: only low 19 bits of the XOR matter -> 32-bit math is exact
    const uint32_t M = 524287u;
    const uint32_t hx0 = (uint32_t)bx;
    const uint32_t hx1 = hx0 + 1u;
    const uint32_t hy0 = (uint32_t)by       * 2654435761u;
    const uint32_t hy1 = (uint32_t)(by + 1) * 2654435761u;
    const uint32_t hz0 = (uint32_t)bz       * 805459861u;
    const uint32_t hz1 = (uint32_t)(bz + 1) * 805459861u;

    const uint32_t yz00 = hy0 ^ hz0, yz01 = hy0 ^ hz1;
    const uint32_t yz10 = hy1 ^ hz0, yz11 = hy1 ^ hz1;

    h[0] = (hx0 ^ yz00) & M;
    h[1] = (hx0 ^ yz01) & M;
    h[2] = (hx0 ^ yz10) & M;
    h[3] = (hx0 ^ yz11) & M;
    h[4] = (hx1 ^ yz00) & M;
    h[5] = (hx1 ^ yz01) & M;
    h[6] = (hx1 ^ yz10) & M;
    h[7] = (hx1 ^ yz11) & M;
}

__device__ __forceinline__ float2 trilerp(const float2 v[8],
                                          float fx, float fy, float fz) {
    const float gx = 1.0f - fx, gy = 1.0f - fy, gz = 1.0f - fz;
    const float w00 = gx * gy, w01 = gx * fy, w10 = fx * gy, w11 = fx * fy;
    float w, f0, f1;
    w = w00 * gz; f0 = w * v[0].x;          f1 = w * v[0].y;
    w = w00 * fz; f0 = fmaf(w, v[1].x, f0); f1 = fmaf(w, v[1].y, f1);
    w = w01 * gz; f0 = fmaf(w, v[2].x, f0); f1 = fmaf(w, v[2].y, f1);
    w = w01 * fz; f0 = fmaf(w, v[3].x, f0); f1 = fmaf(w, v[3].y, f1);
    w = w10 * gz; f0 = fmaf(w, v[4].x, f0); f1 = fmaf(w, v[4].y, f1);
    w = w10 * fz; f0 = fmaf(w, v[5].x, f0); f1 = fmaf(w, v[5].y, f1);
    w = w11 * gz; f0 = fmaf(w, v[6].x, f0); f1 = fmaf(w, v[6].y, f1);
    w = w11 * fz; f0 = fmaf(w, v[7].x, f0); f1 = fmaf(w, v[7].y, f1);
    return make_float2(f0, f1);
}

// ---------------------------------------------------------------------------
// One kernel per big level (levels 7..15): size = 2^19 (pow2 -> 32-bit hash),
// table = 4 MB = exactly one XCD L2. TWO points per thread -> 16 outstanding
// gathers per thread for latency hiding. Streaming traffic (xyz in, ws out)
// is nontemporal so it doesn't evict the pinned table.
// ---------------------------------------------------------------------------
template<int R, uint32_t OFF>
__global__ __launch_bounds__(256, 4) void big_level2(
    const float* __restrict__ xyz,
    const float2* __restrict__ emb,
    float2* __restrict__ ws,      // level-major slice for this level
    int nb)
{
    const int t  = threadIdx.x;
    const int p0 = blockIdx.x * 512 + t;
    const int p1 = p0 + 256;
    const int q0 = p0 < nb ? p0 : nb - 1;
    const int q1 = p1 < nb ? p1 : nb - 1;

    float nxA, nyA, nzA, nxB, nyB, nzB;
    norm_coords(xyz, q0, nxA, nyA, nzA);
    norm_coords(xyz, q1, nxB, nyB, nzB);

    uint32_t hA[8], hB[8];
    float fxA, fyA, fzA, fxB, fyB, fzB;
    big_prep<R>(nxA, nyA, nzA, hA, fxA, fyA, fzA);
    big_prep<R>(nxB, nyB, nzB, hB, fxB, fyB, fzB);

    // issue all 16 gathers back-to-back before any consumption
    float2 vA[8], vB[8];
    #pragma unroll
    for (int c = 0; c < 8; ++c) vA[c] = emb[hA[c] + OFF];
    #pragma unroll
    for (int c = 0; c < 8; ++c) vB[c] = emb[hB[c] + OFF];

    const float2 rA = trilerp(vA, fxA, fyA, fzA);
    const float2 rB = trilerp(vB, fxB, fyB, fzB);

    uint64_t uA, uB;
    memcpy(&uA, &rA, 8);
    memcpy(&uB, &rB, 8);
    if (p0 < nb) __builtin_nontemporal_store(uA, (uint64_t*)ws + p0);
    if (p1 < nb) __builtin_nontemporal_store(uB, (uint64_t*)ws + p1);
}

// ---------------------------------------------------------------------------
// Pack kernel: computes small levels 0..6 inline (tables total 2.47 MB,
// L2-resident), merges big-level results from ws, writes out coalesced via
// per-wave LDS transpose. ws loads are hoisted to the TOP so their HBM
// latency hides under the 7-level small-table computation.
// ---------------------------------------------------------------------------
__global__ __launch_bounds__(256, 4) void pack_small(
    const float* __restrict__ xyz,
    const float2* __restrict__ emb,
    const float2* __restrict__ ws,
    float* __restrict__ out,
    int nb)
{
    constexpr int      kRes[7]  = {16, 20, 25, 32, 40, 50, 64};
    constexpr uint32_t kSize[7] = {4913u, 9261u, 17576u, 35937u, 68921u, 132651u, 274625u};
    constexpr uint32_t kOff[7]  = {0u, 4913u, 14174u, 31750u, 67687u, 136608u, 269259u};

    __shared__ __align__(16) float lds[4 * 64 * 35];

    const int tid  = threadIdx.x;
    const int lane = tid & 63;
    const int wid  = tid >> 6;
    const int p    = blockIdx.x * 256 + tid;
    const int pc   = (p < nb) ? p : (nb - 1);

    // --- hoist big-level ws loads: 9 long-latency HBM reads in flight
    //     during the entire small-level computation below ---
    uint64_t wsv[9];
    #pragma unroll
    for (int l = 0; l < 9; ++l)
        wsv[l] = __builtin_nontemporal_load(
            (const uint64_t*)ws + (size_t)l * nb + pc);

    const float x = xyz[3 * pc + 0];
    const float y = xyz[3 * pc + 1];
    const float z = xyz[3 * pc + 2];

    float* wl = &lds[(wid * 64 + lane) * 35];
    wl[0] = x; wl[1] = y; wl[2] = z;

    const float inv = 1.0f / 1.5f;
    const float nx = (x + 0.75f) * inv;
    const float ny = (y + 0.75f) * inv;
    const float nz = (z + 0.75f) * inv;

    #pragma unroll
    for (int l = 0; l < 7; ++l) {
        const int      r   = kRes[l];
        const float    rf  = (float)r;
        const uint32_t sz  = kSize[l];
        const uint32_t off = kOff[l];

        const float px = nx * rf, py = ny * rf, pz = nz * rf;
        int bx = (int)floorf(px); bx = bx < 0 ? 0 : (bx > r - 1 ? r - 1 : bx);
        int by = (int)floorf(py); by = by < 0 ? 0 : (by > r - 1 ? r - 1 : by);
        int bz = (int)floorf(pz); bz = bz < 0 ? 0 : (bz > r - 1 ? r - 1 : bz);
        const float fx = px - (float)bx;
        const float fy = py - (float)by;
        const float fz = pz - (float)bz;

        const uint64_t hx0 = (uint64_t)(uint32_t)bx;
        const uint64_t hx1 = hx0 + 1u;
        const uint64_t hy0 = (uint64_t)(uint32_t)by       * 2654435761ull;
        const uint64_t hy1 = (uint64_t)(uint32_t)(by + 1) * 2654435761ull;
        const uint64_t hz0 = (uint64_t)(uint32_t)bz       * 805459861ull;
        const uint64_t hz1 = (uint64_t)(uint32_t)(bz + 1) * 805459861ull;

        const uint64_t yz00 = hy0 ^ hz0, yz01 = hy0 ^ hz1;
        const uint64_t yz10 = hy1 ^ hz0, yz11 = hy1 ^ hz1;

        const uint32_t i000 = (uint32_t)((hx0 ^ yz00) % sz) + off;
        const uint32_t i001 = (uint32_t)((hx0 ^ yz01) % sz) + off;
        const uint32_t i010 = (uint32_t)((hx0 ^ yz10) % sz) + off;
        const uint32_t i011 = (uint32_t)((hx0 ^ yz11) % sz) + off;
        const uint32_t i100 = (uint32_t)((hx1 ^ yz00) % sz) + off;
        const uint32_t i101 = (uint32_t)((hx1 ^ yz01) % sz) + off;
        const uint32_t i110 = (uint32_t)((hx1 ^ yz10) % sz) + off;
        const uint32_t i111 = (uint32_t)((hx1 ^ yz11) % sz) + off;

        const float2 v000 = emb[i000];
        const float2 v001 = emb[i001];
        const float2 v010 = emb[i010];
        const float2 v011 = emb[i011];
        const float2 v100 = emb[i100];
        const float2 v101 = emb[i101];
        const float2 v110 = emb[i110];
        const float2 v111 = emb[i111];

        const float gx = 1.0f - fx, gy = 1.0f - fy, gz = 1.0f - fz;
        const float w00 = gx * gy, w01 = gx * fy, w10 = fx * gy, w11 = fx * fy;

        float w, f0, f1;
        w = w00 * gz; f0 = w * v000.x;          f1 = w * v000.y;
        w = w00 * fz; f0 = fmaf(w, v001.x, f0); f1 = fmaf(w, v001.y, f1);
        w = w01 * gz; f0 = fmaf(w, v010.x, f0); f1 = fmaf(w, v010.y, f1);
        w = w01 * fz; f0 = fmaf(w, v011.x, f0); f1 = fmaf(w, v011.y, f1);
        w = w10 * gz; f0 = fmaf(w, v100.x, f0); f1 = fmaf(w, v100.y, f1);
        w = w10 * fz; f0 = fmaf(w, v101.x, f0); f1 = fmaf(w, v101.y, f1);
        w = w11 * gz; f0 = fmaf(w, v110.x, f0); f1 = fmaf(w, v110.y, f1);
        w = w11 * fz; f0 = fmaf(w, v111.x, f0); f1 = fmaf(w, v111.y, f1);

        wl[3 + 2 * l] = f0;
        wl[4 + 2 * l] = f1;
    }

    // big-level results (already in flight since kernel start)
    #pragma unroll
    for (int l = 0; l < 9; ++l) {
        float2 v;
        memcpy(&v, &wsv[l], 8);
        wl[3 + 2 * (l + 7)] = v.x;
        wl[4 + 2 * (l + 7)] = v.y;
    }

    __syncthreads();

    const int wave_gid = blockIdx.x * 4 + wid;
    if (wave_gid * 64 < nb) {
        // straight linear copy of the wave's 64 records (8960 B), float4-wide
        const float4* s4 = (const float4*)&lds[wid * 64 * 35];
        float4* d4 = (float4*)(out + (size_t)wave_gid * (64 * 35));
        #pragma unroll
        for (int c = 0; c < 8; ++c)
            d4[c * 64 + lane] = s4[c * 64 + lane];
        if (lane < 48)
            d4[8 * 64 + lane] = s4[8 * 64 + lane];
    }
}

// ---------------------------------------------------------------------------
// Fallback: round-1 monolithic kernel (used only if ws_size < 72 MB)
// ---------------------------------------------------------------------------
__global__ __launch_bounds__(256, 4) void hashgrid_mono(
    const float* __restrict__ xyz,
    const float2* __restrict__ emb,
    float* __restrict__ out,
    int nb)
{
    constexpr int      kRes[NLEV]  = {16,20,25,32,40,50,64,80,101,128,161,203,256,322,406,512};
    constexpr uint32_t kSize[NLEV] = {4913u,9261u,17576u,35937u,68921u,132651u,274625u,
                                      524288u,524288u,524288u,524288u,524288u,
                                      524288u,524288u,524288u,524288u};
    constexpr uint32_t kOff[NLEV]  = {0u,4913u,14174u,31750u,67687u,136608u,269259u,543884u,
                                      1068172u,1592460u,2116748u,2641036u,3165324u,
                                      3689612u,4213900u,4738188u};

    __shared__ __align__(16) float lds[4 * 64 * 35];

    const int tid  = threadIdx.x;
    const int lane = tid & 63;
    const int wid  = tid >> 6;
    const int p    = blockIdx.x * 256 + tid;
    const int pc   = (p < nb) ? p : (nb - 1);

    const float x = xyz[3 * pc + 0];
    const float y = xyz[3 * pc + 1];
    const float z = xyz[3 * pc + 2];

    float* wl = &lds[(wid * 64 + lane) * 35];
    wl[0] = x; wl[1] = y; wl[2] = z;

    const float inv = 1.0f / 1.5f;
    const float nx = (x + 0.75f) * inv;
    const float ny = (y + 0.75f) * inv;
    const float nz = (z + 0.75f) * inv;

    #pragma unroll
    for (int l = 0; l < NLEV; ++l) {
        const int      r   = kRes[l];
        const float    rf  = (float)r;
        const uint32_t sz  = kSize[l];
        const uint32_t off = kOff[l];

        const float px = nx * rf, py = ny * rf, pz = nz * rf;
        int bx = (int)floorf(px); bx = bx < 0 ? 0 : (bx > r - 1 ? r - 1 : bx);
        int by = (int)floorf(py); by = by < 0 ? 0 : (by > r - 1 ? r - 1 : by);
        int bz = (int)floorf(pz); bz = bz < 0 ? 0 : (bz > r - 1 ? r - 1 : bz);
        const float fx = px - (float)bx;
        const float fy = py - (float)by;
        const float fz = pz - (float)bz;

        const uint64_t hx0 = (uint64_t)(uint32_t)bx;
        const uint64_t hx1 = hx0 + 1u;
        const uint64_t hy0 = (uint64_t)(uint32_t)by       * 2654435761ull;
        const uint64_t hy1 = (uint64_t)(uint32_t)(by + 1) * 2654435761ull;
        const uint64_t hz0 = (uint64_t)(uint32_t)bz       * 805459861ull;
        const uint64_t hz1 = (uint64_t)(uint32_t)(bz + 1) * 805459861ull;

        const uint64_t yz00 = hy0 ^ hz0, yz01 = hy0 ^ hz1;
        const uint64_t yz10 = hy1 ^ hz0, yz11 = hy1 ^ hz1;

        const uint32_t i000 = (uint32_t)((hx0 ^ yz00) % sz) + off;
        const uint32_t i001 = (uint32_t)((hx0 ^ yz01) % sz) + off;
        const uint32_t i010 = (uint32_t)((hx0 ^ yz10) % sz) + off;
        const uint32_t i011 = (uint32_t)((hx0 ^ yz11) % sz) + off;
        const uint32_t i100 = (uint32_t)((hx1 ^ yz00) % sz) + off;
        const uint32_t i101 = (uint32_t)((hx1 ^ yz01) % sz) + off;
        const uint32_t i110 = (uint32_t)((hx1 ^ yz10) % sz) + off;
        const uint32_t i111 = (uint32_t)((hx1 ^ yz11) % sz) + off;

        const float2 v000 = emb[i000];
        const float2 v001 = emb[i001];
        const float2 v010 = emb[i010];
        const float2 v011 = emb[i011];
        const float2 v100 = emb[i100];
        const float2 v101 = emb[i101];
        const float2 v110 = emb[i110];
        const float2 v111 = emb[i111];

        const float gx = 1.0f - fx, gy = 1.0f - fy, gz = 1.0f - fz;
        const float w00 = gx * gy, w01 = gx * fy, w10 = fx * gy, w11 = fx * fy;

        float w, f0, f1;
        w = w00 * gz; f0 = w * v000.x;          f1 = w * v000.y;
        w = w00 * fz; f0 = fmaf(w, v001.x, f0); f1 = fmaf(w, v001.y, f1);
        w = w01 * gz; f0 = fmaf(w, v010.x, f0); f1 = fmaf(w, v010.y, f1);
        w = w01 * fz; f0 = fmaf(w, v011.x, f0); f1 = fmaf(w, v011.y, f1);
        w = w10 * gz; f0 = fmaf(w, v100.x, f0); f1 = fmaf(w, v100.y, f1);
        w = w10 * fz; f0 = fmaf(w, v101.x, f0); f1 = fmaf(w, v101.y, f1);
        w = w11 * gz; f0 = fmaf(w, v110.x, f0); f1 = fmaf(w, v110.y, f1);
        w = w11 * fz; f0 = fmaf(w, v111.x, f0); f1 = fmaf(w, v111.y, f1);

        wl[3 + 2 * l] = f0;
        wl[4 + 2 * l] = f1;
    }

    __syncthreads();

    const int wave_gid = blockIdx.x * 4 + wid;
    if (wave_gid * 64 < nb) {
        const float* src = &lds[wid * 64 * 35];
        float* dst = out + (size_t)wave_gid * (64 * 35);
        #pragma unroll
        for (int c = 0; c < 35; ++c)
            dst[c * 64 + lane] = src[c * 64 + lane];
    }
}

// ---------------------------------------------------------------------------
extern "C" void kernel_launch(void* const* d_in, const int* in_sizes, int n_in,
                              void* d_out, int out_size, void* d_ws, size_t ws_size,
                              hipStream_t stream) {
    const float*  xyz = (const float*)d_in[0];
    const float2* emb = (const float2*)d_in[1];
    float*        out = (float*)d_out;
    const int nb = in_sizes[0] / 3;             // 1,000,000
    const int blocks  = (nb + 255) / 256;       // 3907  (pack)
    const int blocks2 = (nb + 511) / 512;       // 1954  (big levels, 2 pts/thread)

    const size_t ws_need = (size_t)9 * (size_t)nb * sizeof(float2);  // 72 MB
    if (ws_size < ws_need) {
        hashgrid_mono<<<blocks, 256, 0, stream>>>(xyz, emb, out, nb);
        return;
    }

    float2* ws = (float2*)d_ws;
    // levels 7..15: R = {80,101,128,161,203,256,322,406,512}
    big_level2< 80,  543884u><<<blocks2, 256, 0, stream>>>(xyz, emb, ws + (size_t)0 * nb, nb);
    big_level2<101, 1068172u><<<blocks2, 256, 0, stream>>>(xyz, emb, ws + (size_t)1 * nb, nb);
    big_level2<128, 1592460u><<<blocks2, 256, 0, stream>>>(xyz, emb, ws + (size_t)2 * nb, nb);
    big_level2<161, 2116748u><<<blocks2, 256, 0, stream>>>(xyz, emb, ws + (size_t)3 * nb, nb);
    big_level2<203, 2641036u><<<blocks2, 256, 0, stream>>>(xyz, emb, ws + (size_t)4 * nb, nb);
    big_level2<256, 3165324u><<<blocks2, 256, 0, stream>>>(xyz, emb, ws + (size_t)5 * nb, nb);
    big_level2<322, 3689612u><<<blocks2, 256, 0, stream>>>(xyz, emb, ws + (size_t)6 * nb, nb);
    big_level2<406, 4213900u><<<blocks2, 256, 0, stream>>>(xyz, emb, ws + (size_t)7 * nb, nb);
    big_level2<512, 4738188u><<<blocks2, 256, 0, stream>>>(xyz, emb, ws + (size_t)8 * nb, nb);
    pack_small<<<blocks, 256, 0, stream>>>(xyz, emb, ws, out, nb);
}

// Round 3
// 625.180 us; speedup vs baseline: 1.1540x; 1.1540x over previous
//
#include <hip/hip_runtime.h>
#include <stdint.h>
#include <string.h>

#define NLEV 16

typedef float  vfloat4 __attribute__((ext_vector_type(4)));   // nontemporal-store-compatible

// ---------------------------------------------------------------------------
// Shared helpers
// ---------------------------------------------------------------------------
__device__ __forceinline__ void norm_coords(const float* __restrict__ xyz, int p,
                                            float& nx, float& ny, float& nz) {
    const float x = __builtin_nontemporal_load(xyz + 3 * p + 0);
    const float y = __builtin_nontemporal_load(xyz + 3 * p + 1);
    const float z = __builtin_nontemporal_load(xyz + 3 * p + 2);
    const float inv = 1.0f / 1.5f;
    nx = (x + 0.75f) * inv;
    ny = (y + 0.75f) * inv;
    nz = (z + 0.75f) * inv;
}

__device__ __forceinline__ float2 trilerp(const float2 v[8],
                                          float fx, float fy, float fz) {
    const float gx = 1.0f - fx, gy = 1.0f - fy, gz = 1.0f - fz;
    const float w00 = gx * gy, w01 = gx * fy, w10 = fx * gy, w11 = fx * fy;
    float w, f0, f1;
    w = w00 * gz; f0 = w * v[0].x;          f1 = w * v[0].y;
    w = w00 * fz; f0 = fmaf(w, v[1].x, f0); f1 = fmaf(w, v[1].y, f1);
    w = w01 * gz; f0 = fmaf(w, v[2].x, f0); f1 = fmaf(w, v[2].y, f1);
    w = w01 * fz; f0 = fmaf(w, v[3].x, f0); f1 = fmaf(w, v[3].y, f1);
    w = w10 * gz; f0 = fmaf(w, v[4].x, f0); f1 = fmaf(w, v[4].y, f1);
    w = w10 * fz; f0 = fmaf(w, v[5].x, f0); f1 = fmaf(w, v[5].y, f1);
    w = w11 * gz; f0 = fmaf(w, v[6].x, f0); f1 = fmaf(w, v[6].y, f1);
    w = w11 * fz; f0 = fmaf(w, v[7].x, f0); f1 = fmaf(w, v[7].y, f1);
    return make_float2(f0, f1);
}

// ---------------------------------------------------------------------------
// One kernel per big level (levels 7..15): size = 2^19 (pow2 -> 32-bit hash),
// table = 4 MB = one XCD L2. Request-count trick: with x-prime == 1,
// h(x1) = h(x0) ^ 1 whenever bx is even, so the 16B-aligned float4 chunk at
// (h0>>1) holds BOTH x-corners. We issue 4 float4 loads for all lanes and 4
// float2 loads exec-masked to odd-bx lanes only: 6 avg lane-requests/point
// instead of 8. Two points per thread keeps 8+ chunk loads in flight.
// ---------------------------------------------------------------------------
template<int R, uint32_t OFF>
__global__ __launch_bounds__(256, 4) void big_level2(
    const float* __restrict__ xyz,
    const float2* __restrict__ emb,
    float2* __restrict__ ws,      // level-major slice for this level
    int nb)
{
    const int t  = threadIdx.x;
    const int p0 = blockIdx.x * 512 + t;
    const int p1 = p0 + 256;
    const int q[2] = { p0 < nb ? p0 : nb - 1, p1 < nb ? p1 : nb - 1 };

    const float4* __restrict__ emb4 = (const float4*)emb;
    const uint32_t M = 524287u;

    uint32_t h0[2][4];
    uint32_t yzs[2][4];
    uint32_t hx1_[2];
    float4   V[2][4];
    float2   w1[2][4];
    float    fx[2], fy[2], fz[2];
    bool     oddbx[2];

    // phase 1: address math + issue all float4 chunk loads (8 in flight)
    #pragma unroll
    for (int j = 0; j < 2; ++j) {
        float nx, ny, nz;
        norm_coords(xyz, q[j], nx, ny, nz);
        const float rf = (float)R;
        const float px = nx * rf, py = ny * rf, pz = nz * rf;
        int bx = (int)floorf(px); bx = bx < 0 ? 0 : (bx > R - 1 ? R - 1 : bx);
        int by = (int)floorf(py); by = by < 0 ? 0 : (by > R - 1 ? R - 1 : by);
        int bz = (int)floorf(pz); bz = bz < 0 ? 0 : (bz > R - 1 ? R - 1 : bz);
        fx[j] = px - (float)bx;
        fy[j] = py - (float)by;
        fz[j] = pz - (float)bz;

        const uint32_t hy0 = (uint32_t)by       * 2654435761u;
        const uint32_t hy1 = (uint32_t)(by + 1) * 2654435761u;
        const uint32_t hz0 = (uint32_t)bz       * 805459861u;
        const uint32_t hz1 = (uint32_t)(bz + 1) * 805459861u;
        yzs[j][0] = hy0 ^ hz0; yzs[j][1] = hy0 ^ hz1;
        yzs[j][2] = hy1 ^ hz0; yzs[j][3] = hy1 ^ hz1;

        const uint32_t hx0 = (uint32_t)bx;
        oddbx[j] = (bx & 1) != 0;
        hx1_[j]  = hx0 + 1u;

        #pragma unroll
        for (int i = 0; i < 4; ++i) {
            h0[j][i] = (hx0 ^ yzs[j][i]) & M;
            V[j][i]  = emb4[(h0[j][i] >> 1) + (OFF >> 1)];
        }
    }

    // phase 2: odd-bx lanes fetch the 4 x1-corners they can't get from chunks
    #pragma unroll
    for (int j = 0; j < 2; ++j) {
        if (oddbx[j]) {
            #pragma unroll
            for (int i = 0; i < 4; ++i)
                w1[j][i] = emb[((hx1_[j] ^ yzs[j][i]) & M) + OFF];
        }
    }

    // phase 3: select halves + interpolate
    float2 r[2];
    #pragma unroll
    for (int j = 0; j < 2; ++j) {
        float2 v[8];
        #pragma unroll
        for (int i = 0; i < 4; ++i) {
            const float2 lo = make_float2(V[j][i].x, V[j][i].y);
            const float2 hi = make_float2(V[j][i].z, V[j][i].w);
            const bool oh = (h0[j][i] & 1u) != 0u;
            v[i]     = oh ? hi : lo;
            v[i + 4] = oddbx[j] ? w1[j][i] : (oh ? lo : hi);
        }
        r[j] = trilerp(v, fx[j], fy[j], fz[j]);
    }

    uint64_t u0, u1;
    memcpy(&u0, &r[0], 8);
    memcpy(&u1, &r[1], 8);
    if (p0 < nb) __builtin_nontemporal_store(u0, (uint64_t*)ws + p0);
    if (p1 < nb) __builtin_nontemporal_store(u1, (uint64_t*)ws + p1);
}

// ---------------------------------------------------------------------------
// Pack kernel: computes small levels 0..6 inline (tables total 2.47 MB,
// L2-resident), merges big-level results from ws, writes out coalesced via
// per-wave LDS transpose. Software-pipelined depth 2: level l+1's 8 gathers
// are issued before level l's trilerp consumes, so 16 gathers + 9 ws loads
// stay in flight. Buffer index (l&1) is compile-time after full unroll.
// ---------------------------------------------------------------------------
__global__ __launch_bounds__(256, 4) void pack_small(
    const float* __restrict__ xyz,
    const float2* __restrict__ emb,
    const float2* __restrict__ ws,
    float* __restrict__ out,
    int nb)
{
    constexpr int      kRes[7]  = {16, 20, 25, 32, 40, 50, 64};
    constexpr uint32_t kSize[7] = {4913u, 9261u, 17576u, 35937u, 68921u, 132651u, 274625u};
    constexpr uint32_t kOff[7]  = {0u, 4913u, 14174u, 31750u, 67687u, 136608u, 269259u};

    __shared__ __align__(16) float lds[4 * 64 * 35];

    const int tid  = threadIdx.x;
    const int lane = tid & 63;
    const int wid  = tid >> 6;
    const int p    = blockIdx.x * 256 + tid;
    const int pc   = (p < nb) ? p : (nb - 1);

    // --- hoist big-level ws loads: 9 long-latency HBM reads in flight
    //     during the entire small-level computation below ---
    uint64_t wsv[9];
    #pragma unroll
    for (int l = 0; l < 9; ++l)
        wsv[l] = __builtin_nontemporal_load(
            (const uint64_t*)ws + (size_t)l * nb + pc);

    const float x = xyz[3 * pc + 0];
    const float y = xyz[3 * pc + 1];
    const float z = xyz[3 * pc + 2];

    float* wl = &lds[(wid * 64 + lane) * 35];
    wl[0] = x; wl[1] = y; wl[2] = z;

    const float inv = 1.0f / 1.5f;
    const float nx = (x + 0.75f) * inv;
    const float ny = (y + 0.75f) * inv;
    const float nz = (z + 0.75f) * inv;

    uint32_t idx[2][8];
    float2   v[2][8];
    float    fr[2][3];

    // index computation for one level (lv is a constant after unroll)
    auto level_idx = [&](int lv, uint32_t (&ix)[8], float (&f)[3]) {
        const int      r   = kRes[lv];
        const float    rf  = (float)r;
        const uint32_t sz  = kSize[lv];
        const uint32_t off = kOff[lv];

        const float px = nx * rf, py = ny * rf, pz = nz * rf;
        int bx = (int)floorf(px); bx = bx < 0 ? 0 : (bx > r - 1 ? r - 1 : bx);
        int by = (int)floorf(py); by = by < 0 ? 0 : (by > r - 1 ? r - 1 : by);
        int bz = (int)floorf(pz); bz = bz < 0 ? 0 : (bz > r - 1 ? r - 1 : bz);
        f[0] = px - (float)bx;
        f[1] = py - (float)by;
        f[2] = pz - (float)bz;

        const uint64_t hx0 = (uint64_t)(uint32_t)bx;
        const uint64_t hx1 = hx0 + 1u;
        const uint64_t hy0 = (uint64_t)(uint32_t)by       * 2654435761ull;
        const uint64_t hy1 = (uint64_t)(uint32_t)(by + 1) * 2654435761ull;
        const uint64_t hz0 = (uint64_t)(uint32_t)bz       * 805459861ull;
        const uint64_t hz1 = (uint64_t)(uint32_t)(bz + 1) * 805459861ull;

        const uint64_t yz00 = hy0 ^ hz0, yz01 = hy0 ^ hz1;
        const uint64_t yz10 = hy1 ^ hz0, yz11 = hy1 ^ hz1;

        ix[0] = (uint32_t)((hx0 ^ yz00) % sz) + off;
        ix[1] = (uint32_t)((hx0 ^ yz01) % sz) + off;
        ix[2] = (uint32_t)((hx0 ^ yz10) % sz) + off;
        ix[3] = (uint32_t)((hx0 ^ yz11) % sz) + off;
        ix[4] = (uint32_t)((hx1 ^ yz00) % sz) + off;
        ix[5] = (uint32_t)((hx1 ^ yz01) % sz) + off;
        ix[6] = (uint32_t)((hx1 ^ yz10) % sz) + off;
        ix[7] = (uint32_t)((hx1 ^ yz11) % sz) + off;
    };

    // prologue: level 0
    level_idx(0, idx[0], fr[0]);
    #pragma unroll
    for (int i = 0; i < 8; ++i) v[0][i] = emb[idx[0][i]];

    #pragma unroll
    for (int l = 0; l < 7; ++l) {
        const int cur = l & 1;
        const int nxt = cur ^ 1;
        if (l < 6) {
            level_idx(l + 1, idx[nxt], fr[nxt]);
            #pragma unroll
            for (int i = 0; i < 8; ++i) v[nxt][i] = emb[idx[nxt][i]];
        }
        const float2 rr = trilerp(v[cur], fr[cur][0], fr[cur][1], fr[cur][2]);
        wl[3 + 2 * l] = rr.x;
        wl[4 + 2 * l] = rr.y;
    }

    // big-level results (in flight since kernel start)
    #pragma unroll
    for (int l = 0; l < 9; ++l) {
        float2 bv;
        memcpy(&bv, &wsv[l], 8);
        wl[3 + 2 * (l + 7)] = bv.x;
        wl[4 + 2 * (l + 7)] = bv.y;
    }

    __syncthreads();

    const int wave_gid = blockIdx.x * 4 + wid;
    if (wave_gid * 64 < nb) {
        // straight linear copy of the wave's 64 records (8960 B), float4-wide,
        // nontemporal so the 140 MB output stream doesn't evict small tables
        const vfloat4* s4 = (const vfloat4*)&lds[wid * 64 * 35];
        vfloat4* d4 = (vfloat4*)(out + (size_t)wave_gid * (64 * 35));
        #pragma unroll
        for (int c = 0; c < 8; ++c)
            __builtin_nontemporal_store(s4[c * 64 + lane], &d4[c * 64 + lane]);
        if (lane < 48)
            __builtin_nontemporal_store(s4[8 * 64 + lane], &d4[8 * 64 + lane]);
    }
}

// ---------------------------------------------------------------------------
// Fallback: monolithic kernel (used only if ws_size < 72 MB)
// ---------------------------------------------------------------------------
__global__ __launch_bounds__(256, 4) void hashgrid_mono(
    const float* __restrict__ xyz,
    const float2* __restrict__ emb,
    float* __restrict__ out,
    int nb)
{
    constexpr int      kRes[NLEV]  = {16,20,25,32,40,50,64,80,101,128,161,203,256,322,406,512};
    constexpr uint32_t kSize[NLEV] = {4913u,9261u,17576u,35937u,68921u,132651u,274625u,
                                      524288u,524288u,524288u,524288u,524288u,
                                      524288u,524288u,524288u,524288u};
    constexpr uint32_t kOff[NLEV]  = {0u,4913u,14174u,31750u,67687u,136608u,269259u,543884u,
                                      1068172u,1592460u,2116748u,2641036u,3165324u,
                                      3689612u,4213900u,4738188u};

    __shared__ __align__(16) float lds[4 * 64 * 35];

    const int tid  = threadIdx.x;
    const int lane = tid & 63;
    const int wid  = tid >> 6;
    const int p    = blockIdx.x * 256 + tid;
    const int pc   = (p < nb) ? p : (nb - 1);

    const float x = xyz[3 * pc + 0];
    const float y = xyz[3 * pc + 1];
    const float z = xyz[3 * pc + 2];

    float* wl = &lds[(wid * 64 + lane) * 35];
    wl[0] = x; wl[1] = y; wl[2] = z;

    const float inv = 1.0f / 1.5f;
    const float nx = (x + 0.75f) * inv;
    const float ny = (y + 0.75f) * inv;
    const float nz = (z + 0.75f) * inv;

    #pragma unroll
    for (int l = 0; l < NLEV; ++l) {
        const int      r   = kRes[l];
        const float    rf  = (float)r;
        const uint32_t sz  = kSize[l];
        const uint32_t off = kOff[l];

        const float px = nx * rf, py = ny * rf, pz = nz * rf;
        int bx = (int)floorf(px); bx = bx < 0 ? 0 : (bx > r - 1 ? r - 1 : bx);
        int by = (int)floorf(py); by = by < 0 ? 0 : (by > r - 1 ? r - 1 : by);
        int bz = (int)floorf(pz); bz = bz < 0 ? 0 : (bz > r - 1 ? r - 1 : bz);
        const float fx = px - (float)bx;
        const float fy = py - (float)by;
        const float fz = pz - (float)bz;

        const uint64_t hx0 = (uint64_t)(uint32_t)bx;
        const uint64_t hx1 = hx0 + 1u;
        const uint64_t hy0 = (uint64_t)(uint32_t)by       * 2654435761ull;
        const uint64_t hy1 = (uint64_t)(uint32_t)(by + 1) * 2654435761ull;
        const uint64_t hz0 = (uint64_t)(uint32_t)bz       * 805459861ull;
        const uint64_t hz1 = (uint64_t)(uint32_t)(bz + 1) * 805459861ull;

        const uint64_t yz00 = hy0 ^ hz0, yz01 = hy0 ^ hz1;
        const uint64_t yz10 = hy1 ^ hz0, yz11 = hy1 ^ hz1;

        const uint32_t i000 = (uint32_t)((hx0 ^ yz00) % sz) + off;
        const uint32_t i001 = (uint32_t)((hx0 ^ yz01) % sz) + off;
        const uint32_t i010 = (uint32_t)((hx0 ^ yz10) % sz) + off;
        const uint32_t i011 = (uint32_t)((hx0 ^ yz11) % sz) + off;
        const uint32_t i100 = (uint32_t)((hx1 ^ yz00) % sz) + off;
        const uint32_t i101 = (uint32_t)((hx1 ^ yz01) % sz) + off;
        const uint32_t i110 = (uint32_t)((hx1 ^ yz10) % sz) + off;
        const uint32_t i111 = (uint32_t)((hx1 ^ yz11) % sz) + off;

        const float2 v000 = emb[i000];
        const float2 v001 = emb[i001];
        const float2 v010 = emb[i010];
        const float2 v011 = emb[i011];
        const float2 v100 = emb[i100];
        const float2 v101 = emb[i101];
        const float2 v110 = emb[i110];
        const float2 v111 = emb[i111];

        const float gx = 1.0f - fx, gy = 1.0f - fy, gz = 1.0f - fz;
        const float w00 = gx * gy, w01 = gx * fy, w10 = fx * gy, w11 = fx * fy;

        float w, f0, f1;
        w = w00 * gz; f0 = w * v000.x;          f1 = w * v000.y;
        w = w00 * fz; f0 = fmaf(w, v001.x, f0); f1 = fmaf(w, v001.y, f1);
        w = w01 * gz; f0 = fmaf(w, v010.x, f0); f1 = fmaf(w, v010.y, f1);
        w = w01 * fz; f0 = fmaf(w, v011.x, f0); f1 = fmaf(w, v011.y, f1);
        w = w10 * gz; f0 = fmaf(w, v100.x, f0); f1 = fmaf(w, v100.y, f1);
        w = w10 * fz; f0 = fmaf(w, v101.x, f0); f1 = fmaf(w, v101.y, f1);
        w = w11 * gz; f0 = fmaf(w, v110.x, f0); f1 = fmaf(w, v110.y, f1);
        w = w11 * fz; f0 = fmaf(w, v111.x, f0); f1 = fmaf(w, v111.y, f1);

        wl[3 + 2 * l] = f0;
        wl[4 + 2 * l] = f1;
    }

    __syncthreads();

    const int wave_gid = blockIdx.x * 4 + wid;
    if (wave_gid * 64 < nb) {
        const float* src = &lds[wid * 64 * 35];
        float* dst = out + (size_t)wave_gid * (64 * 35);
        #pragma unroll
        for (int c = 0; c < 35; ++c)
            dst[c * 64 + lane] = src[c * 64 + lane];
    }
}

// ---------------------------------------------------------------------------
extern "C" void kernel_launch(void* const* d_in, const int* in_sizes, int n_in,
                              void* d_out, int out_size, void* d_ws, size_t ws_size,
                              hipStream_t stream) {
    const float*  xyz = (const float*)d_in[0];
    const float2* emb = (const float2*)d_in[1];
    float*        out = (float*)d_out;
    const int nb = in_sizes[0] / 3;             // 1,000,000
    const int blocks  = (nb + 255) / 256;       // 3907  (pack)
    const int blocks2 = (nb + 511) / 512;       // 1954  (big levels, 2 pts/thread)

    const size_t ws_need = (size_t)9 * (size_t)nb * sizeof(float2);  // 72 MB
    if (ws_size < ws_need) {
        hashgrid_mono<<<blocks, 256, 0, stream>>>(xyz, emb, out, nb);
        return;
    }

    float2* ws = (float2*)d_ws;
    // levels 7..15: R = {80,101,128,161,203,256,322,406,512}
    big_level2< 80,  543884u><<<blocks2, 256, 0, stream>>>(xyz, emb, ws + (size_t)0 * nb, nb);
    big_level2<101, 1068172u><<<blocks2, 256, 0, stream>>>(xyz, emb, ws + (size_t)1 * nb, nb);
    big_level2<128, 1592460u><<<blocks2, 256, 0, stream>>>(xyz, emb, ws + (size_t)2 * nb, nb);
    big_level2<161, 2116748u><<<blocks2, 256, 0, stream>>>(xyz, emb, ws + (size_t)3 * nb, nb);
    big_level2<203, 2641036u><<<blocks2, 256, 0, stream>>>(xyz, emb, ws + (size_t)4 * nb, nb);
    big_level2<256, 3165324u><<<blocks2, 256, 0, stream>>>(xyz, emb, ws + (size_t)5 * nb, nb);
    big_level2<322, 3689612u><<<blocks2, 256, 0, stream>>>(xyz, emb, ws + (size_t)6 * nb, nb);
    big_level2<406, 4213900u><<<blocks2, 256, 0, stream>>>(xyz, emb, ws + (size_t)7 * nb, nb);
    big_level2<512, 4738188u><<<blocks2, 256, 0, stream>>>(xyz, emb, ws + (size_t)8 * nb, nb);
    pack_small<<<blocks, 256, 0, stream>>>(xyz, emb, ws, out, nb);
}